// Round 10
// baseline (337.427 us; speedup 1.0000x reference)
//
#include <hip/hip_runtime.h>
#include <stdint.h>

typedef __bf16 bf16_t;
typedef bf16_t bf16x8 __attribute__((ext_vector_type(8)));
typedef float f32x4 __attribute__((ext_vector_type(4)));
typedef uint32_t u32x4 __attribute__((ext_vector_type(4)));
typedef uint16_t u16x8 __attribute__((ext_vector_type(8)));

union FragU { u32x4 u; bf16x8 v; u16x8 s; };

__device__ __forceinline__ uint16_t f2bf_rne(float f) {
  uint32_t u = __float_as_uint(f);
  return (uint16_t)((u + 0x7fffu + ((u >> 16) & 1u)) >> 16);
}
__device__ __forceinline__ float bf2f_bits(uint16_t h) {
  return __uint_as_float(((uint32_t)h) << 16);
}

// ---------------------------------------------------------------------------
// Kernel 1: pack W (512x52 f32) into MFMA B-fragment layout, bf16 hi + lo.
// B-frag for mfma_f32_16x16x32_bf16: lane l holds B[k][n], n = nt*16+(l&15),
// k = ks*32 + (l>>4)*8 + j. N padded 52->64. ws: wf_hi[4096] + wf_lo[4096].
// ---------------------------------------------------------------------------
__global__ __launch_bounds__(256) void pack_w_kernel(
    const float* __restrict__ W, u32x4* __restrict__ wf_hi,
    u32x4* __restrict__ wf_lo) {
  int idx = blockIdx.x * 256 + threadIdx.x;
  if (idx >= 4096) return;
  int lane = idx & 63;
  int nt   = (idx >> 6) & 3;
  int ks   = idx >> 8;
  int n  = nt * 16 + (lane & 15);
  int kb = ks * 32 + (lane >> 4) * 8;
  FragU hi, lo;
#pragma unroll
  for (int j = 0; j < 8; ++j) {
    float w = (n < 52) ? W[(kb + j) * 52 + n] : 0.0f;
    uint16_t h = f2bf_rne(w);
    hi.s[j] = h;
    lo.s[j] = f2bf_rne(w - bf2f_bits(h));
  }
  wf_hi[idx] = hi.u;
  wf_lo[idx] = lo.u;
}

#define MFMA16(a, b, c) __builtin_amdgcn_mfma_f32_16x16x32_bf16((a), (b), (c), 0, 0, 0)

// ---------------------------------------------------------------------------
// Kernel 2: fused GEMM + bias + softmax(13) + rule mix — SEQUENTIAL-READ form.
// Block = 32 rows (contiguous 64 KB of z). 4 waves SPLIT K: wave w owns
// K-chunks {p*8 + w*2, +1} per phase p. Phase stages 32 rows x 1 KB
// CONTIGUOUS runs via global_load_lds (src pre-swizzled col^=(row&7)<<4;
// reads XOR the same). Partial accs reduced via LDS (wave0 write + atomicAdd).
// LDS = 32768 B exactly -> 5 blocks/CU, 20 waves/CU.
// ---------------------------------------------------------------------------
__global__ __launch_bounds__(256, 5) void raven_main_kernel(
    const float* __restrict__ z, const float* __restrict__ xq,
    const u32x4* __restrict__ wfh, const u32x4* __restrict__ wfl,
    const float* __restrict__ bias, float* __restrict__ out) {
  __shared__ __align__(16) unsigned char smem[32768];  // staging / logits union

  const int tid  = threadIdx.x;
  const int wave = tid >> 6;
  const int lane = tid & 63;
  const int r  = lane & 15;   // A row within 16-tile / C col
  const int kg = lane >> 4;   // k-group (8 contiguous k per lane)

  const long long brow = (long long)blockIdx.x * 32;
  const float* zb = z + brow * 512;

  f32x4 acc[2][4];
#pragma unroll
  for (int mt = 0; mt < 2; ++mt)
#pragma unroll
    for (int nt = 0; nt < 4; ++nt) {
      f32x4 zv = {0.0f, 0.0f, 0.0f, 0.0f};
      acc[mt][nt] = zv;
    }

  const int lfo = lane * 4;        // lane float offset within a 1 KB row-run
  const int sw  = (r & 7) << 4;    // read-side swizzle (row r and r+16 share it)

#pragma unroll
  for (int p = 0; p < 2; ++p) {
    // ---- stage phase p: wave w loads rows [w*8, w*8+8), 1 KB each, all
    // contiguous 1 KB global runs (16 B/lane, src col pre-swizzled) ----
#pragma unroll
    for (int i = 0; i < 8; ++i) {
      const int row = wave * 8 + i;
      const float* src = zb + row * 512 + p * 256 + (lfo ^ ((row & 7) * 4));
      __builtin_amdgcn_global_load_lds(
          (const __attribute__((address_space(1))) void*)src,
          (__attribute__((address_space(3))) void*)(smem + row * 1024),
          16, 0, 0);
    }
    __syncthreads();  // drains vmcnt(0): all 32 rows staged

    const int kbase = p * 8 + wave * 2;
#pragma unroll
    for (int c = 0; c < 2; ++c) {
      const int ksg = kbase + c;          // global K-chunk for B-frags
      FragU bh[4], bl[4];
      const u32x4* ph = wfh + ksg * 256 + lane;
      const u32x4* pl = wfl + ksg * 256 + lane;
#pragma unroll
      for (int nt = 0; nt < 4; ++nt) {
        bh[nt].u = ph[nt * 64];
        bl[nt].u = pl[nt * 64];
      }

      // A-frags from LDS: row-stride 1024 B, col = klocal*128 + kg*32 (+16)
      const int colb = (wave * 2 + c) * 128 + kg * 32;
      const unsigned char* c0 = smem + r * 1024;
      const unsigned char* c1 = smem + (r + 16) * 1024;
      f32x4 a00 = *(const f32x4*)(c0 + ((colb     ) ^ sw));
      f32x4 a01 = *(const f32x4*)(c0 + ((colb + 16) ^ sw));
      f32x4 a10 = *(const f32x4*)(c1 + ((colb     ) ^ sw));
      f32x4 a11 = *(const f32x4*)(c1 + ((colb + 16) ^ sw));

      FragU h0, h1;
#pragma unroll
      for (int j = 0; j < 4; ++j) {
        h0.v[j]     = (bf16_t)a00[j];
        h0.v[4 + j] = (bf16_t)a01[j];
        h1.v[j]     = (bf16_t)a10[j];
        h1.v[4 + j] = (bf16_t)a11[j];
      }

#pragma unroll
      for (int nt = 0; nt < 4; ++nt) {
        acc[0][nt] = MFMA16(h0.v, bh[nt].v, acc[0][nt]);
        acc[0][nt] = MFMA16(h0.v, bl[nt].v, acc[0][nt]);
        acc[1][nt] = MFMA16(h1.v, bh[nt].v, acc[1][nt]);
        acc[1][nt] = MFMA16(h1.v, bl[nt].v, acc[1][nt]);
      }
    }
    __syncthreads();  // all waves done reading before buffer reuse
  }

  // ---- cross-wave K-reduction into logits[32][65] (staging area dead) ----
  // C layout: col = lane&15, row = (lane>>4)*4 + i  [m89-verified]
  float (*logits)[65] = (float(*)[65])smem;
  if (wave == 0) {
#pragma unroll
    for (int mt = 0; mt < 2; ++mt)
#pragma unroll
      for (int nt = 0; nt < 4; ++nt)
#pragma unroll
        for (int i = 0; i < 4; ++i)
          logits[mt * 16 + kg * 4 + i][nt * 16 + r] = acc[mt][nt][i];
  }
  __syncthreads();
  if (wave != 0) {
#pragma unroll
    for (int mt = 0; mt < 2; ++mt)
#pragma unroll
      for (int nt = 0; nt < 4; ++nt)
#pragma unroll
        for (int i = 0; i < 4; ++i)
          atomicAdd(&logits[mt * 16 + kg * 4 + i][nt * 16 + r], acc[mt][nt][i]);
  }
  __syncthreads();

  // ---- epilogue: one thread per row (32 rows), vectorized xq/out ----
  // rules = [a, b-2, b-1, b+1, b+2, a-b, a+b, min, max, b+2, b+1, b-2, b-1]
  if (tid < 32) {
    const int row = tid;
    const long long grow = brow + row;
    f32x4 xa = *(const f32x4*)(xq + grow * 8);      // a, groups 0..3
    f32x4 xb = *(const f32x4*)(xq + grow * 8 + 4);  // b, groups 0..3
    f32x4 res;
#pragma unroll
    for (int g = 0; g < 4; ++g) {
      float a  = xa[g];
      float bq = xb[g];
      float l[13];
      float m = -1e30f;
#pragma unroll
      for (int u = 0; u < 13; ++u) {
        l[u] = logits[row][g * 13 + u] + bias[g * 13 + u];
        m = fmaxf(m, l[u]);
      }
      float s = 0.0f;
#pragma unroll
      for (int u = 0; u < 13; ++u) {
        float e = __expf(l[u] - m);
        l[u] = e;
        s += e;
      }
      float num = a * l[0]
                + (bq - 2.0f) * (l[1] + l[11])
                + (bq - 1.0f) * (l[2] + l[12])
                + (bq + 1.0f) * (l[3] + l[10])
                + (bq + 2.0f) * (l[4] + l[9])
                + (a - bq) * l[5]
                + (a + bq) * l[6]
                + fminf(a, bq) * l[7]
                + fmaxf(a, bq) * l[8];
      res[g] = num / s;
    }
    *(f32x4*)(out + grow * 4) = res;
  }
}

extern "C" void kernel_launch(void* const* d_in, const int* in_sizes, int n_in,
                              void* d_out, int out_size, void* d_ws, size_t ws_size,
                              hipStream_t stream) {
  const float* z    = (const float*)d_in[0];  // (B, 512)
  const float* xq   = (const float*)d_in[1];  // (B, 2, 4)
  const float* W    = (const float*)d_in[2];  // (512, 52)
  const float* bias = (const float*)d_in[3];  // (52,)
  float* out = (float*)d_out;                 // (B, 1, 4)

  const int B = in_sizes[0] / 512;            // 262144

  u32x4* wf_hi = (u32x4*)d_ws;
  u32x4* wf_lo = wf_hi + 4096;

  hipLaunchKernelGGL(pack_w_kernel, dim3(16), dim3(256), 0, stream, W, wf_hi, wf_lo);

  const int blocks = B / 32;                  // 8192
  hipLaunchKernelGGL(raven_main_kernel, dim3(blocks), dim3(256), 0, stream,
                     z, xq, (const u32x4*)wf_hi, (const u32x4*)wf_lo, bias, out);
}

// Round 11
// 108.949 us; speedup vs baseline: 3.0971x; 3.0971x over previous
//
#include <hip/hip_runtime.h>
#include <stdint.h>

typedef __bf16 bf16_t;
typedef bf16_t bf16x8 __attribute__((ext_vector_type(8)));
typedef float f32x4 __attribute__((ext_vector_type(4)));
typedef uint32_t u32x4 __attribute__((ext_vector_type(4)));
typedef uint16_t u16x8 __attribute__((ext_vector_type(8)));

union FragU { u32x4 u; bf16x8 v; u16x8 s; };

__device__ __forceinline__ uint16_t f2bf_rne(float f) {
  uint32_t u = __float_as_uint(f);
  return (uint16_t)((u + 0x7fffu + ((u >> 16) & 1u)) >> 16);
}

// ---------------------------------------------------------------------------
// Kernel 1: pack W (512x52 f32) into MFMA B-fragment layout, single bf16.
// B-frag for mfma_f32_16x16x32_bf16: lane l holds B[k][n], n = nt*16+(l&15),
// k = ks*32 + (l>>4)*8 + j. N padded 52->64. ws: wf[4096] u32x4 (64 KB).
// ---------------------------------------------------------------------------
__global__ __launch_bounds__(256) void pack_w_kernel(
    const float* __restrict__ W, u32x4* __restrict__ wf) {
  int idx = blockIdx.x * 256 + threadIdx.x;
  if (idx >= 4096) return;
  int lane = idx & 63;
  int nt   = (idx >> 6) & 3;
  int ks   = idx >> 8;
  int n  = nt * 16 + (lane & 15);
  int kb = ks * 32 + (lane >> 4) * 8;
  FragU hi;
#pragma unroll
  for (int j = 0; j < 8; ++j) {
    float w = (n < 52) ? W[(kb + j) * 52 + n] : 0.0f;
    hi.s[j] = f2bf_rne(w);
  }
  wf[idx] = hi.u;
}

#define MFMA16(a, b, c) __builtin_amdgcn_mfma_f32_16x16x32_bf16((a), (b), (c), 0, 0, 0)

// ---------------------------------------------------------------------------
// Kernel 2: fused GEMM + bias + softmax(13) + rule mix.
// r8 structure, W single-bf16: per iter 4 stage + 4 B-loads + 8 MFMA.
// Split waits: vmcnt(8) [drain stage(ks); B(ks)+stage(ks+1) in flight]
// -> ds_read+cvt -> vmcnt(4) [drain B(ks)] -> MFMA -> issue LOADB(ks+1),
// STAGE(ks+2). FIFO at iter top: [stage(ks) 4, B(ks) 4, stage(ks+1) 4].
// LDS union: staging [4 waves][2][4096 B] = 32 KB  /  logits[128][65] f32.
// ---------------------------------------------------------------------------
__global__ __launch_bounds__(256, 4) void raven_main_kernel(
    const float* __restrict__ z, const float* __restrict__ xq,
    const u32x4* __restrict__ wfh,
    const float* __restrict__ bias, float* __restrict__ out) {
  __shared__ __align__(16) unsigned char smem[33280];  // max(32768, 128*65*4)
  __shared__ float lds_bias[52];

  const int tid  = threadIdx.x;
  const int wave = tid >> 6;
  const int lane = tid & 63;
  const int r  = lane & 15;   // A row within 16-tile / C col
  const int kg = lane >> 4;   // k-group (8 contiguous k per lane)

  if (tid < 52) lds_bias[tid] = bias[tid];

  const long long brow = (long long)blockIdx.x * 128;
  const long long wrow = brow + (long long)wave * 32;
  const float* zb = z + wrow * 512;

  unsigned char* stg = smem + wave * 8192;  // [2][4096]

  // staging: lane covers bytes [(lane&7)*16,+16) of row (i*8 + (lane>>3));
  // source col pre-swizzled: foff = 4*((lane&7)^rloc)  (HW-verified r6)
  const int rloc = lane >> 3;
  const int foff = 4 * ((lane & 7) ^ rloc);

  f32x4 acc[2][4];
#pragma unroll
  for (int mt = 0; mt < 2; ++mt)
#pragma unroll
    for (int nt = 0; nt < 4; ++nt) {
      f32x4 zv = {0.0f, 0.0f, 0.0f, 0.0f};
      acc[mt][nt] = zv;
    }

#define STAGE_CHUNK(ks_, buf_)                                                  \
  {                                                                             \
    const float* g_ = zb + rloc * 512 + (ks_) * 32 + foff;                      \
    _Pragma("unroll")                                                           \
    for (int i_ = 0; i_ < 4; ++i_)                                              \
      __builtin_amdgcn_global_load_lds(                                         \
          (const __attribute__((address_space(1))) void*)(g_ + i_ * 8 * 512),   \
          (__attribute__((address_space(3))) void*)((buf_) + i_ * 1024),        \
          16, 0, 0);                                                            \
  }

#define LOADB(ks_)                                                              \
  {                                                                             \
    const u32x4* ph_ = wfh + (ks_) * 256 + lane;                                \
    _Pragma("unroll")                                                           \
    for (int nt_ = 0; nt_ < 4; ++nt_) {                                         \
      bh[nt_].u = ph_[nt_ * 64];                                                \
    }                                                                           \
  }

  FragU bh[4];

  // prologue (retirement order): stage(0) < B(0) < stage(1)
  STAGE_CHUNK(0, stg);
  LOADB(0);
  STAGE_CHUNK(1, stg + 4096);

  const int swz = (r & 7) << 4;

#pragma unroll
  for (int ks = 0; ks < 16; ++ks) {
    unsigned char* cur = stg + (ks & 1) * 4096;

    // wait 1: drain stage(ks) only; B(ks)(4) + stage(ks+1)(4) stay in flight
    if (ks < 15) asm volatile("s_waitcnt vmcnt(8)" ::: "memory");
    else         asm volatile("s_waitcnt vmcnt(4)" ::: "memory");
    __builtin_amdgcn_sched_barrier(0);

    // A-frags from LDS (swizzled ds_read_b128), convert to bf16 —
    // this work executes under B(ks)'s L2 latency.
    const unsigned char* c0 = cur + r * 128;
    const unsigned char* c1 = cur + (r + 16) * 128;
    f32x4 a00 = *(const f32x4*)(c0 + ((kg * 32) ^ swz));
    f32x4 a01 = *(const f32x4*)(c0 + ((kg * 32 + 16) ^ swz));
    f32x4 a10 = *(const f32x4*)(c1 + ((kg * 32) ^ swz));
    f32x4 a11 = *(const f32x4*)(c1 + ((kg * 32 + 16) ^ swz));

    FragU h0, h1;
#pragma unroll
    for (int j = 0; j < 4; ++j) {
      h0.v[j]     = (bf16_t)a00[j];
      h0.v[4 + j] = (bf16_t)a01[j];
      h1.v[j]     = (bf16_t)a10[j];
      h1.v[4 + j] = (bf16_t)a11[j];
    }
    __builtin_amdgcn_sched_barrier(0);

    // wait 2: drain B(ks); stage(ks+1) stays in flight
    if (ks < 15) asm volatile("s_waitcnt vmcnt(4)" ::: "memory");
    else         asm volatile("s_waitcnt vmcnt(0)" ::: "memory");
    __builtin_amdgcn_sched_barrier(0);

#pragma unroll
    for (int nt = 0; nt < 4; ++nt) {
      acc[0][nt] = MFMA16(h0.v, bh[nt].v, acc[0][nt]);
      acc[1][nt] = MFMA16(h1.v, bh[nt].v, acc[1][nt]);
    }
    __builtin_amdgcn_sched_barrier(0);

    // issue next-iter operands AFTER the MFMAs consumed bh (no rename):
    // retirement order stays stage < B < stage.
    if (ks < 15) LOADB(ks + 1);
    if (ks < 14) STAGE_CHUNK(ks + 2, cur);  // cur's ds_reads retired above
  }
#undef STAGE_CHUNK
#undef LOADB

  // staging area is dead only after ALL waves finish their K-loop
  __syncthreads();

  float (*lds)[65] = (float(*)[65])smem;  // logits tile aliases staging

  // C layout: col = lane&15, row = (lane>>4)*4 + i  [m89-verified]
#pragma unroll
  for (int mt = 0; mt < 2; ++mt)
#pragma unroll
    for (int nt = 0; nt < 4; ++nt)
#pragma unroll
      for (int i = 0; i < 4; ++i)
        lds[wave * 32 + mt * 16 + kg * 4 + i][nt * 16 + r] = acc[mt][nt][i];

  __syncthreads();

  // Epilogue: one thread per row, vectorized xq/out. Per group: softmax(13)
  // + rule mix. rules = [a,b-2,b-1,b+1,b+2,a-b,a+b,min,max,b+2,b+1,b-2,b-1]
  if (tid < 128) {
    int row = tid;
    long long grow = brow + row;
    f32x4 xa = *(const f32x4*)(xq + grow * 8);      // a, groups 0..3
    f32x4 xb = *(const f32x4*)(xq + grow * 8 + 4);  // b, groups 0..3
    f32x4 res;
#pragma unroll
    for (int g = 0; g < 4; ++g) {
      float a  = xa[g];
      float bq = xb[g];
      float l[13];
      float m = -1e30f;
#pragma unroll
      for (int u = 0; u < 13; ++u) {
        l[u] = lds[row][g * 13 + u] + lds_bias[g * 13 + u];
        m = fmaxf(m, l[u]);
      }
      float s = 0.0f;
#pragma unroll
      for (int u = 0; u < 13; ++u) {
        float e = __expf(l[u] - m);
        l[u] = e;
        s += e;
      }
      float num = a * l[0]
                + (bq - 2.0f) * (l[1] + l[11])
                + (bq - 1.0f) * (l[2] + l[12])
                + (bq + 1.0f) * (l[3] + l[10])
                + (bq + 2.0f) * (l[4] + l[9])
                + (a - bq) * l[5]
                + (a + bq) * l[6]
                + fminf(a, bq) * l[7]
                + fmaxf(a, bq) * l[8];
      res[g] = num / s;
    }
    *(f32x4*)(out + grow * 4) = res;
  }
}

extern "C" void kernel_launch(void* const* d_in, const int* in_sizes, int n_in,
                              void* d_out, int out_size, void* d_ws, size_t ws_size,
                              hipStream_t stream) {
  const float* z    = (const float*)d_in[0];  // (B, 512)
  const float* xq   = (const float*)d_in[1];  // (B, 2, 4)
  const float* W    = (const float*)d_in[2];  // (512, 52)
  const float* bias = (const float*)d_in[3];  // (52,)
  float* out = (float*)d_out;                 // (B, 1, 4)

  const int B = in_sizes[0] / 512;            // 262144

  u32x4* wf = (u32x4*)d_ws;

  hipLaunchKernelGGL(pack_w_kernel, dim3(16), dim3(256), 0, stream, W, wf);

  const int blocks = B / 128;                 // 2048
  hipLaunchKernelGGL(raven_main_kernel, dim3(blocks), dim3(256), 0, stream,
                     z, xq, (const u32x4*)wf, bias, out);
}